// Round 11
// baseline (272.832 us; speedup 1.0000x reference)
//
#include <hip/hip_runtime.h>
#include <hip/hip_bf16.h>
#include <stdint.h>

// ---------------------------------------------------------------------------
// MHA forward, bf16 MFMA path (gfx950).  B=1, S=4096, D=1024, H=16, HD=64.
//   1. preprocess: cast x->bf16 + transpose-cast Wq|Wk|Wv, Wo
//   2. gemm_qkv: BK=32 (R10 A/B: BK=64+swizzle had 0 bank conflicts but
//      non-flash time 129->137 us — 32KB LDS cut blocks/CU; BK=32 wins).
//      Q -> Qb[4096][1024] pre-scaled 0.125*log2e; K,V -> fragment-packed
//      Kf/Vf (R16): flash reads become dense 1KB wave-reads.
//   3. flash_attn ROUND-20: R10 measured VGPR 124 + 64 AGPR = 188 combined
//      -> 2 waves/SIMD; SIMD issue only ~45% busy (66 tile-waves x 760 cyc
//      = 21 us ideal vs 46.5 measured). Fix: 3rd wave/SIMD via (256,3)
//      (cap 170) + single-V buffer (-16 regs; packed-V loads are dense L2
//      hits arriving under the ~600-cyc softmax window — R2's JIT-V failure
//      was with 16-segment scattered loads, not these). K ping-pong kept.
//      Spill detector: WRITE_SIZE >> 8MB => allocator missed 106 arch regs.
//   4. gemm_out: R7 version (BK=32, 64x128 tiles).
//   Ledger: R0 75 | R2 140 | R3 spill 256 | R4 occ31% 133 | R7 packed 49 |
//   R10 BK64 46.5+0-conflict but net -5 -> flash tracks issue-port+segments.
// ---------------------------------------------------------------------------

typedef __bf16 bf16;
typedef __bf16 bf16x4 __attribute__((ext_vector_type(4)));
typedef __bf16 bf16x8 __attribute__((ext_vector_type(8)));
typedef float  f32x4  __attribute__((ext_vector_type(4)));

#define MFMA32(a, b, c) __builtin_amdgcn_mfma_f32_16x16x32_bf16((a), (b), (c), 0, 0, 0)

static constexpr int S_LEN  = 4096;
static constexpr int DMODEL = 1024;
static constexpr int HDIM   = 64;

#define GLOAD_LDS16(g, l)                                                      \
  __builtin_amdgcn_global_load_lds((__attribute__((address_space(1))) void*)(g), \
                                   (__attribute__((address_space(3))) void*)(l), 16, 0, 0)

// ------------- fused preprocess: cast x + 4 weight transposes --------------
__global__ __launch_bounds__(256) void preprocess(const float* __restrict__ x,
                                                  const float* __restrict__ Wq,
                                                  const float* __restrict__ Wk,
                                                  const float* __restrict__ Wv,
                                                  const float* __restrict__ Wo,
                                                  bf16* __restrict__ xb,
                                                  bf16* __restrict__ Wt,
                                                  bf16* __restrict__ Wot) {
  __shared__ float tile[64][65];
  const int t = threadIdx.x, b = blockIdx.x;
  if (b < 1024) {
#pragma unroll
    for (int i = 0; i < 4; i++) {
      int idx = b * 1024 + i * 256 + t;
      float4 v = ((const float4*)x)[idx];
      bf16x4 o;
      o[0] = (bf16)v.x; o[1] = (bf16)v.y; o[2] = (bf16)v.z; o[3] = (bf16)v.w;
      ((bf16x4*)xb)[idx] = o;
    }
    return;
  }
  const int id = b - 1024;
  const int wsel = id >> 8;
  const int t2 = id & 255;
  const int kb = (t2 & 15) * 64, nb = (t2 >> 4) * 64;
  const float* src = (wsel == 0) ? Wq : (wsel == 1) ? Wk : (wsel == 2) ? Wv : Wo;
  bf16* dst = (wsel < 3) ? (Wt + (size_t)wsel * 1024 * 1024) : Wot;
#pragma unroll
  for (int i = 0; i < 16; i++) {
    int idx = t + i * 256;
    int r = idx >> 6, c = idx & 63;
    tile[r][c] = src[(size_t)(kb + r) * 1024 + nb + c];
  }
  __syncthreads();
#pragma unroll
  for (int i = 0; i < 16; i++) {
    int idx = t + i * 256;
    int cc = idx >> 6, rr = idx & 63;
    dst[(size_t)(nb + cc) * 1024 + kb + rr] = (bf16)tile[rr][cc];
  }
}

// ------------------- gemm_qkv: 128x128 tile, K=1024, BK=32 -----------------
// R7 version. Outputs:
//   n0 <  1024 : Qb[row][col] = acc * 0.18033688 (0.125*log2e), stride 1024
//   n0 <  2048 : Kf packed (R16 layout)
//   else       : Vf packed (R16 layout)
__global__ __launch_bounds__(256) void gemm_qkv(const bf16* __restrict__ A,
                                                const bf16* __restrict__ Bt,
                                                bf16* __restrict__ Qb,
                                                bf16* __restrict__ Kf,
                                                bf16* __restrict__ Vf) {
  __shared__ bf16 lsA[128 * 32];
  __shared__ bf16 lsB[128 * 32];
  const int tid = threadIdx.x, w = tid >> 6, lane = tid & 63;
  const int l15 = lane & 15, quad = lane >> 4;
  const int m0 = blockIdx.x * 128, n0 = blockIdx.y * 128;
  const int wm = (w >> 1) * 64, wn = (w & 1) * 64;
  const int rowA = lane >> 2;
  const int colk = (((lane & 3) ^ ((lane >> 3) & 3))) * 8;  // inverse-swizzled src
  const int rsl = (l15 >> 1) & 3;                           // read-side swizzle

  f32x4 acc[4][4] = {};

  for (int k0 = 0; k0 < 1024; k0 += 32) {
    __syncthreads();
#pragma unroll
    for (int i = 0; i < 2; i++) {
      int s = w * 2 + i;
      const bf16* ga = A + (size_t)(m0 + s * 16 + rowA) * 1024 + k0 + colk;
      GLOAD_LDS16(ga, lsA + s * 512);
      const bf16* gb = Bt + (size_t)(n0 + s * 16 + rowA) * 1024 + k0 + colk;
      GLOAD_LDS16(gb, lsB + s * 512);
    }
    __syncthreads();

    bf16x8 af[4], bfr[4];
#pragma unroll
    for (int r = 0; r < 4; r++)
      af[r] = *(const bf16x8*)(lsA + (wm + r * 16 + l15) * 32 + (quad ^ rsl) * 8);
#pragma unroll
    for (int c = 0; c < 4; c++)
      bfr[c] = *(const bf16x8*)(lsB + (wn + c * 16 + l15) * 32 + (quad ^ rsl) * 8);
#pragma unroll
    for (int r = 0; r < 4; r++)
#pragma unroll
      for (int c = 0; c < 4; c++)
        acc[r][c] = MFMA32(af[r], bfr[c], acc[r][c]);
  }

  if (n0 < 1024) {
    // ---- Q ----
#pragma unroll
    for (int r = 0; r < 4; r++) {
#pragma unroll
      for (int c = 0; c < 4; c++) {
        int col = n0 + wn + c * 16 + l15;
#pragma unroll
        for (int e = 0; e < 4; e++) {
          int row = m0 + wm + r * 16 + quad * 4 + e;
          Qb[(size_t)row * 1024 + col] = (bf16)(acc[r][c][e] * 0.18033688f);
        }
      }
    }
  } else if (n0 < 2048) {
    // ---- K packed ----
    const int h  = (n0 - 1024 + wn) >> 6;
    const int g0 = (m0 + wm) >> 5;
    bf16* base = Kf + (size_t)(h * 128 + g0) * 2048 +
                 (quad & 1) * 1024 + (l15 >> 3) * 128 + (quad >> 1) * 32 + (l15 & 7);
#pragma unroll
    for (int r = 0; r < 4; r++) {
#pragma unroll
      for (int c = 0; c < 4; c++) {
#pragma unroll
        for (int e = 0; e < 4; e++) {
          base[(r >> 1) * 2048 + (r & 1) * 64 + (c >> 1) * 512 + (c & 1) * 256 + e * 8] =
              (bf16)acc[r][c][e];
        }
      }
    }
  } else {
    // ---- V packed ----
    const int h  = (n0 - 2048 + wn) >> 6;
    const int g0 = (m0 + wm) >> 5;
    bf16* base = Vf + (size_t)(h * 128 + g0) * 2048 +
                 (quad >> 1) * 128 + l15 * 8 + (quad & 1) * 4;
#pragma unroll
    for (int r = 0; r < 4; r++) {
#pragma unroll
      for (int c = 0; c < 4; c++) {
        bf16x4 pk;
#pragma unroll
        for (int e = 0; e < 4; e++) pk[e] = (bf16)acc[r][c][e];
        *(bf16x4*)(base + (r >> 1) * 2048 + (r & 1) * 256 + c * 512) = pk;
      }
    }
  }
}

// ----------------------------- flash attention -----------------------------
// 1024 blocks, one 64-q tile each, 4 key-split waves, packed K/V (dense 1KB
// wave-reads). ROUND-20: (256,3) for 3 waves/SIMD — single-V buffer drops
// arch regs 124 -> ~106 so combined (incl. 64 AGPR oacc) fits the 170 cap.
// V load issued between QK and softmax; consumed ~600 cyc later by PV.
__global__ __launch_bounds__(256, 3) void flash_attn(const bf16* __restrict__ Qb,
                                                     const bf16* __restrict__ Kf,
                                                     const bf16* __restrict__ Vf,
                                                     bf16* __restrict__ Ctx) {
  __shared__ float Obuf[4][16][68];   // 17.4 KB: per-wave partial O, one qg chunk
  __shared__ float Lbuf[4][4][64];    // 4 KB
  const int tid = threadIdx.x, w = tid >> 6, lane = tid & 63;
  const int l15 = lane & 15, quad = lane >> 4;
  const int i = blockIdx.x;
  const int head = (i & 7) + 8 * ((i >> 3) & 1);
  const int qt_raw = i >> 4;
  const int qb = (qt_raw < 32) ? qt_raw : (95 - qt_raw);
  const int hq = head * HDIM;

  const int T = (qb >> 1) + 1;              // 128-key tiles

  // Packed per-wave base pointers: group g = j*4 + w.
  const bf16* Kw = Kf + (size_t)(head * 128 + w) * 2048 + lane * 8;
  const bf16* Vw = Vf + (size_t)(head * 128 + w) * 2048 + lane * 8;

  // Q frags (B-operand): q = qb*64 + qg*16 + l15, d = kk*32 + quad*8 + j
  bf16x8 qf[4][2];
#pragma unroll
  for (int qg = 0; qg < 4; qg++)
#pragma unroll
    for (int kk = 0; kk < 2; kk++)
      qf[qg][kk] = *(const bf16x8*)(Qb + (size_t)(qb * 64 + qg * 16 + l15) * 1024 +
                                    hq + kk * 32 + quad * 8);

  f32x4 oacc[4][4] = {};
  float lsum[4] = {0.f, 0.f, 0.f, 0.f};

  auto load_k = [&](int j, bf16x8 (&kf)[2][2]) {
#pragma unroll
    for (int c = 0; c < 2; c++)
#pragma unroll
      for (int kk = 0; kk < 2; kk++)
        kf[c][kk] = *(const bf16x8*)(Kw + j * 8192 + c * 1024 + kk * 512);
  };
  auto compute = [&](int j, bf16x8 (&kf)[2][2]) {
    // S^T = K Q^T : C row = key-slot quad*4+e (matrix c), col = q = l15
    f32x4 sacc[2][4] = {};
    __builtin_amdgcn_s_setprio(1);
#pragma unroll
    for (int kk = 0; kk < 2; kk++)
#pragma unroll
      for (int c = 0; c < 2; c++)
#pragma unroll
        for (int qg = 0; qg < 4; qg++)
          sacc[c][qg] = MFMA32(kf[c][kk], qf[qg][kk], sacc[c][qg]);
    __builtin_amdgcn_s_setprio(0);

    // single-V buffer: dense 1KB wave-read issued here, consumed after the
    // ~600-cycle softmax below (L2 hit ~200 cyc -> fully hidden).
    bf16x8 vf[4];
#pragma unroll
    for (int dg = 0; dg < 4; dg++)
      vf[dg] = *(const bf16x8*)(Vw + j * 8192 + dg * 512);

    bf16x8 pfr[4];
    if (j == T - 1) {
      const int kb0 = j * 128 + w * 32 + quad * 8;   // + 4c + e = actual key
#pragma unroll
      for (int qg = 0; qg < 4; qg++) {
        const int qrow = qb * 64 + qg * 16 + l15;
        bf16x8 pb;
#pragma unroll
        for (int c = 0; c < 2; c++)
#pragma unroll
          for (int e = 0; e < 4; e++) {
            float s = sacc[c][qg][e];
            if (kb0 + 4 * c + e > qrow) s = -1e30f;
            float pv = __builtin_amdgcn_exp2f(s);
            lsum[qg] += pv;
            pb[c * 4 + e] = (bf16)pv;
          }
        pfr[qg] = pb;
      }
    } else {
#pragma unroll
      for (int qg = 0; qg < 4; qg++) {
        bf16x8 pb;
#pragma unroll
        for (int c = 0; c < 2; c++)
#pragma unroll
          for (int e = 0; e < 4; e++) {
            float pv = __builtin_amdgcn_exp2f(sacc[c][qg][e]);
            lsum[qg] += pv;
            pb[c * 4 + e] = (bf16)pv;
          }
        pfr[qg] = pb;
      }
    }

    // O += P V  (K=32, P direct from registers)
    __builtin_amdgcn_s_setprio(1);
#pragma unroll
    for (int qg = 0; qg < 4; qg++)
#pragma unroll
      for (int dg = 0; dg < 4; dg++)
        oacc[qg][dg] = MFMA32(pfr[qg], vf[dg], oacc[qg][dg]);
    __builtin_amdgcn_s_setprio(0);
  };

  bf16x8 kfA[2][2], kfB[2][2];
  load_k(0, kfA);
  for (int j = 0; j < T; j += 2) {
    if (j + 1 < T) load_k(j + 1, kfB);
    compute(j, kfA);
    if (j + 2 < T) load_k(j + 2, kfA);
    if (j + 1 < T) compute(j + 1, kfB);
  }

  // ---- chunked cross-wave reduction: one qg (16 q-rows) at a time ----
#pragma unroll
  for (int qg = 0; qg < 4; qg++)
    Lbuf[w][quad][qg * 16 + l15] = lsum[qg];

  const int row = tid >> 4;               // 0..15 (local q within chunk)
  const int col = (tid & 15) * 4;         // 0..60 (d within head)
  for (int qg = 0; qg < 4; qg++) {
#pragma unroll
    for (int dg = 0; dg < 4; dg++)
#pragma unroll
      for (int e = 0; e < 4; e++)
        Obuf[w][quad * 4 + e][dg * 16 + l15] = oacc[qg][dg][e];
    __syncthreads();                      // writes visible
    f32x4 os = {};
#pragma unroll
    for (int ww = 0; ww < 4; ww++)
      os += *(const f32x4*)&Obuf[ww][row][col];
    float lr = 0.f;
#pragma unroll
    for (int ww = 0; ww < 4; ww++)
#pragma unroll
      for (int qq = 0; qq < 4; qq++)
        lr += Lbuf[ww][qq][qg * 16 + row];
    const float linv = 1.f / lr;
    bf16x4 ob;
#pragma unroll
    for (int e2 = 0; e2 < 4; e2++) ob[e2] = (bf16)(os[e2] * linv);
    *(bf16x4*)(Ctx + (size_t)(qb * 64 + qg * 16 + row) * DMODEL + hq + col) = ob;
    __syncthreads();                      // reads done before next chunk
  }
}

// ---------------- gemm_out: 64x128 tile, K=1024, BK=32, swizzled -----------
__global__ __launch_bounds__(256) void gemm_out(const bf16* __restrict__ A,
                                                const bf16* __restrict__ Bt,
                                                float* __restrict__ C,
                                                const float* __restrict__ bias) {
  __shared__ bf16 lsA[64 * 32];
  __shared__ bf16 lsB[128 * 32];
  const int tid = threadIdx.x, w = tid >> 6, lane = tid & 63;
  const int l15 = lane & 15, quad = lane >> 4;
  const int m0 = blockIdx.x * 64, n0 = blockIdx.y * 128;
  const int wm = (w >> 1) * 32, wn = (w & 1) * 64;
  const int rowA = lane >> 2;
  const int colk = (((lane & 3) ^ ((lane >> 3) & 3))) * 8;  // inverse-swizzled src
  const int rsl = (l15 >> 1) & 3;                           // read-side swizzle

  f32x4 acc[2][4] = {};

  for (int k0 = 0; k0 < 1024; k0 += 32) {
    __syncthreads();
#pragma unroll
    for (int i = 0; i < 3; i++) {
      int s = w * 3 + i;
      if (s < 4) {
        const bf16* ga = A + (size_t)(m0 + s * 16 + rowA) * 1024 + k0 + colk;
        GLOAD_LDS16(ga, lsA + s * 512);
      } else {
        const bf16* gb = Bt + (size_t)(n0 + (s - 4) * 16 + rowA) * 1024 + k0 + colk;
        GLOAD_LDS16(gb, lsB + (s - 4) * 512);
      }
    }
    __syncthreads();

    bf16x8 af[2], bfr[4];
#pragma unroll
    for (int r = 0; r < 2; r++)
      af[r] = *(const bf16x8*)(lsA + (wm + r * 16 + l15) * 32 + (quad ^ rsl) * 8);
#pragma unroll
    for (int c = 0; c < 4; c++)
      bfr[c] = *(const bf16x8*)(lsB + (wn + c * 16 + l15) * 32 + (quad ^ rsl) * 8);
#pragma unroll
    for (int r = 0; r < 2; r++)
#pragma unroll
      for (int c = 0; c < 4; c++)
        acc[r][c] = MFMA32(af[r], bfr[c], acc[r][c]);
  }

#pragma unroll
  for (int r = 0; r < 2; r++) {
#pragma unroll
    for (int c = 0; c < 4; c++) {
      int col = n0 + wn + c * 16 + l15;
#pragma unroll
      for (int e = 0; e < 4; e++) {
        int row = m0 + wm + r * 16 + quad * 4 + e;
        C[(size_t)row * 1024 + col] = acc[r][c][e] + bias[col];
      }
    }
  }
}

// ------------------------------- launcher ----------------------------------
extern "C" void kernel_launch(void* const* d_in, const int* in_sizes, int n_in,
                              void* d_out, int out_size, void* d_ws, size_t ws_size,
                              hipStream_t stream) {
  const float* x  = (const float*)d_in[0];
  const float* Wq = (const float*)d_in[1];
  const float* Wk = (const float*)d_in[2];
  const float* Wv = (const float*)d_in[3];
  const float* Wo = (const float*)d_in[4];
  const float* bo = (const float*)d_in[5];

  char* ws = (char*)d_ws;                    // 48 MB total
  bf16* xb  = (bf16*)(ws);                   // 8 MB  [4096][1024]
  bf16* Wt  = (bf16*)(ws + (8u  << 20));     // 6 MB  [3072][1024]
  bf16* Wot = (bf16*)(ws + (14u << 20));     // 2 MB  [1024][1024]
  bf16* Qb  = (bf16*)(ws + (16u << 20));     // 8 MB  [4096][1024]
  bf16* Kf  = (bf16*)(ws + (24u << 20));     // 8 MB  packed K frags
  bf16* Vf  = (bf16*)(ws + (32u << 20));     // 8 MB  packed V frags
  bf16* Ctx = (bf16*)(ws + (40u << 20));     // 8 MB  [4096][1024]

  preprocess<<<2048, 256, 0, stream>>>(x, Wq, Wk, Wv, Wo, xb, Wt, Wot);
  gemm_qkv<<<dim3(32, 24), 256, 0, stream>>>(xb, Wt, Qb, Kf, Vf);
  flash_attn<<<1024, 256, 0, stream>>>(Qb, Kf, Vf, Ctx);
  gemm_out<<<dim3(64, 8), 256, 0, stream>>>(Ctx, Wot, (float*)d_out, bo);
}

// Round 12
// 184.309 us; speedup vs baseline: 1.4803x; 1.4803x over previous
//
#include <hip/hip_runtime.h>
#include <hip/hip_bf16.h>
#include <stdint.h>

// ---------------------------------------------------------------------------
// MHA forward, bf16 MFMA path (gfx950).  B=1, S=4096, D=1024, H=16, HD=64.
//   1. preprocess: cast x->bf16 + transpose-cast Wq|Wk|Wv, Wo
//   2. gemm_qkv: R7 version (BK=32; R10 A/B showed BK=64 is net -5 us).
//      Q -> Qb[4096][1024] pre-scaled 0.125*log2e; K,V fragment-packed.
//   3. flash_attn ROUND-21: R4 geometry + R16 packed layouts.
//      Register ledger law (3 spill disasters: R3, R11): 64q geometry floor
//      = 188 combined -> 2 waves/SIMD forever; forcing min-waves with <15
//      regs margin cascades into 300+ MB scratch. R4's 32q geometry measured
//      84 arch + 32 AGPR = 116 clean at (256,3) — only its SCATTERED loads
//      made it slow (17.7M segments). Packed Kf/Vf fixes that: dense 1KB
//      wave-reads. So: 2048 blocks (32q each), 4 key-split waves, K ping-
//      pong, V issued between QK and softmax (~200cyc L2 hides under ~400cyc
//      SM), LPT order, XCD-local heads, dead-wave early exit.
//      L2 budget: 1.1GB tile traffic ~ 3.9 TB/s/XCD at 36us < 4.3 ceiling.
//   4. gemm_out: R7 version (BK=32, 64x128 tiles).
//   Ledger: R0 75 | R2 140 | R3 spill | R4 occ31% 133 | R7 packed 46.5-49 |
//   R10 BK64 net-5 | R11 spill 142. Flash tracks segments + resident waves.
// ---------------------------------------------------------------------------

typedef __bf16 bf16;
typedef __bf16 bf16x4 __attribute__((ext_vector_type(4)));
typedef __bf16 bf16x8 __attribute__((ext_vector_type(8)));
typedef float  f32x4  __attribute__((ext_vector_type(4)));

#define MFMA32(a, b, c) __builtin_amdgcn_mfma_f32_16x16x32_bf16((a), (b), (c), 0, 0, 0)

static constexpr int S_LEN  = 4096;
static constexpr int DMODEL = 1024;
static constexpr int HDIM   = 64;

#define GLOAD_LDS16(g, l)                                                      \
  __builtin_amdgcn_global_load_lds((__attribute__((address_space(1))) void*)(g), \
                                   (__attribute__((address_space(3))) void*)(l), 16, 0, 0)

// ------------- fused preprocess: cast x + 4 weight transposes --------------
__global__ __launch_bounds__(256) void preprocess(const float* __restrict__ x,
                                                  const float* __restrict__ Wq,
                                                  const float* __restrict__ Wk,
                                                  const float* __restrict__ Wv,
                                                  const float* __restrict__ Wo,
                                                  bf16* __restrict__ xb,
                                                  bf16* __restrict__ Wt,
                                                  bf16* __restrict__ Wot) {
  __shared__ float tile[64][65];
  const int t = threadIdx.x, b = blockIdx.x;
  if (b < 1024) {
#pragma unroll
    for (int i = 0; i < 4; i++) {
      int idx = b * 1024 + i * 256 + t;
      float4 v = ((const float4*)x)[idx];
      bf16x4 o;
      o[0] = (bf16)v.x; o[1] = (bf16)v.y; o[2] = (bf16)v.z; o[3] = (bf16)v.w;
      ((bf16x4*)xb)[idx] = o;
    }
    return;
  }
  const int id = b - 1024;
  const int wsel = id >> 8;
  const int t2 = id & 255;
  const int kb = (t2 & 15) * 64, nb = (t2 >> 4) * 64;
  const float* src = (wsel == 0) ? Wq : (wsel == 1) ? Wk : (wsel == 2) ? Wv : Wo;
  bf16* dst = (wsel < 3) ? (Wt + (size_t)wsel * 1024 * 1024) : Wot;
#pragma unroll
  for (int i = 0; i < 16; i++) {
    int idx = t + i * 256;
    int r = idx >> 6, c = idx & 63;
    tile[r][c] = src[(size_t)(kb + r) * 1024 + nb + c];
  }
  __syncthreads();
#pragma unroll
  for (int i = 0; i < 16; i++) {
    int idx = t + i * 256;
    int cc = idx >> 6, rr = idx & 63;
    dst[(size_t)(nb + cc) * 1024 + kb + rr] = (bf16)tile[rr][cc];
  }
}

// ------------------- gemm_qkv: 128x128 tile, K=1024, BK=32 -----------------
// R7 version. Outputs:
//   n0 <  1024 : Qb[row][col] = acc * 0.18033688 (0.125*log2e), stride 1024
//   n0 <  2048 : Kf packed (R16 layout)
//   else       : Vf packed (R16 layout)
__global__ __launch_bounds__(256) void gemm_qkv(const bf16* __restrict__ A,
                                                const bf16* __restrict__ Bt,
                                                bf16* __restrict__ Qb,
                                                bf16* __restrict__ Kf,
                                                bf16* __restrict__ Vf) {
  __shared__ bf16 lsA[128 * 32];
  __shared__ bf16 lsB[128 * 32];
  const int tid = threadIdx.x, w = tid >> 6, lane = tid & 63;
  const int l15 = lane & 15, quad = lane >> 4;
  const int m0 = blockIdx.x * 128, n0 = blockIdx.y * 128;
  const int wm = (w >> 1) * 64, wn = (w & 1) * 64;
  const int rowA = lane >> 2;
  const int colk = (((lane & 3) ^ ((lane >> 3) & 3))) * 8;  // inverse-swizzled src
  const int rsl = (l15 >> 1) & 3;                           // read-side swizzle

  f32x4 acc[4][4] = {};

  for (int k0 = 0; k0 < 1024; k0 += 32) {
    __syncthreads();
#pragma unroll
    for (int i = 0; i < 2; i++) {
      int s = w * 2 + i;
      const bf16* ga = A + (size_t)(m0 + s * 16 + rowA) * 1024 + k0 + colk;
      GLOAD_LDS16(ga, lsA + s * 512);
      const bf16* gb = Bt + (size_t)(n0 + s * 16 + rowA) * 1024 + k0 + colk;
      GLOAD_LDS16(gb, lsB + s * 512);
    }
    __syncthreads();

    bf16x8 af[4], bfr[4];
#pragma unroll
    for (int r = 0; r < 4; r++)
      af[r] = *(const bf16x8*)(lsA + (wm + r * 16 + l15) * 32 + (quad ^ rsl) * 8);
#pragma unroll
    for (int c = 0; c < 4; c++)
      bfr[c] = *(const bf16x8*)(lsB + (wn + c * 16 + l15) * 32 + (quad ^ rsl) * 8);
#pragma unroll
    for (int r = 0; r < 4; r++)
#pragma unroll
      for (int c = 0; c < 4; c++)
        acc[r][c] = MFMA32(af[r], bfr[c], acc[r][c]);
  }

  if (n0 < 1024) {
    // ---- Q ----
#pragma unroll
    for (int r = 0; r < 4; r++) {
#pragma unroll
      for (int c = 0; c < 4; c++) {
        int col = n0 + wn + c * 16 + l15;
#pragma unroll
        for (int e = 0; e < 4; e++) {
          int row = m0 + wm + r * 16 + quad * 4 + e;
          Qb[(size_t)row * 1024 + col] = (bf16)(acc[r][c][e] * 0.18033688f);
        }
      }
    }
  } else if (n0 < 2048) {
    // ---- K packed ----
    const int h  = (n0 - 1024 + wn) >> 6;
    const int g0 = (m0 + wm) >> 5;
    bf16* base = Kf + (size_t)(h * 128 + g0) * 2048 +
                 (quad & 1) * 1024 + (l15 >> 3) * 128 + (quad >> 1) * 32 + (l15 & 7);
#pragma unroll
    for (int r = 0; r < 4; r++) {
#pragma unroll
      for (int c = 0; c < 4; c++) {
#pragma unroll
        for (int e = 0; e < 4; e++) {
          base[(r >> 1) * 2048 + (r & 1) * 64 + (c >> 1) * 512 + (c & 1) * 256 + e * 8] =
              (bf16)acc[r][c][e];
        }
      }
    }
  } else {
    // ---- V packed ----
    const int h  = (n0 - 2048 + wn) >> 6;
    const int g0 = (m0 + wm) >> 5;
    bf16* base = Vf + (size_t)(h * 128 + g0) * 2048 +
                 (quad >> 1) * 128 + l15 * 8 + (quad & 1) * 4;
#pragma unroll
    for (int r = 0; r < 4; r++) {
#pragma unroll
      for (int c = 0; c < 4; c++) {
        bf16x4 pk;
#pragma unroll
        for (int e = 0; e < 4; e++) pk[e] = (bf16)acc[r][c][e];
        *(bf16x4*)(base + (r >> 1) * 2048 + (r & 1) * 256 + c * 512) = pk;
      }
    }
  }
}

// ----------------------------- flash attention -----------------------------
// ROUND-21: 2048 blocks x 256 thr. Block i: head=(i&7)+8*((i>>3)&1)
// (XCD-local), qb = 127-(i>>4) (LPT; 2x oversubscription -> backfill).
// Block = 32 q-rows, 128-key tiles, wave w owns keys w*32..+32 (packed
// group g = j*4+w -> dense 1KB wave-reads). T = qb/4+1; wave w with
// w > qb%4 is fully masked on the last tile and exits one tile early.
// K ping-pong; V single-buffer issued between QK and softmax. (256,3):
// R4 measured this geometry at 84 arch + 32 AGPR, ~35 regs under the cap.
__global__ __launch_bounds__(256, 3) void flash_attn(const bf16* __restrict__ Qb,
                                                     const bf16* __restrict__ Kf,
                                                     const bf16* __restrict__ Vf,
                                                     bf16* __restrict__ Ctx) {
  __shared__ float Obuf[4][16][68];   // 17.4 KB: per-wave partial O, 16-row chunk
  __shared__ float Lbuf[4][4][32];    // 2 KB
  const int tid = threadIdx.x, w = tid >> 6, lane = tid & 63;
  const int l15 = lane & 15, quad = lane >> 4;
  const int i = blockIdx.x;
  const int head = (i & 7) + 8 * ((i >> 3) & 1);
  const int qb = 127 - (i >> 4);                             // 0..127
  const int hq = head * HDIM;
  const int q0 = qb * 32;
  const int T = (qb >> 2) + 1;                               // 128-key tiles
  const int Tw = T - ((w > (qb & 3)) ? 1 : 0);               // dead-wave skip

  // Packed per-wave base pointers: group g = j*4 + w.
  const bf16* Kw = Kf + (size_t)(head * 128 + w) * 2048 + lane * 8;
  const bf16* Vw = Vf + (size_t)(head * 128 + w) * 2048 + lane * 8;

  // Q frags (B-operand): q = q0 + qg*16 + l15, d = kk*32 + quad*8 + j
  bf16x8 qf[2][2];
#pragma unroll
  for (int qg = 0; qg < 2; qg++)
#pragma unroll
    for (int kk = 0; kk < 2; kk++)
      qf[qg][kk] = *(const bf16x8*)(Qb + (size_t)(q0 + qg * 16 + l15) * 1024 +
                                    hq + kk * 32 + quad * 8);

  f32x4 oacc[2][4] = {};
  float lsum[2] = {0.f, 0.f};

  auto load_k = [&](int j, bf16x8 (&kf)[2][2]) {
#pragma unroll
    for (int c = 0; c < 2; c++)
#pragma unroll
      for (int kk = 0; kk < 2; kk++)
        kf[c][kk] = *(const bf16x8*)(Kw + j * 8192 + c * 1024 + kk * 512);
  };
  auto compute = [&](int j, bf16x8 (&kf)[2][2]) {
    // S^T = K Q^T : C row = key-slot quad*4+e (c group), col = q = l15
    f32x4 sacc[2][2] = {};
    __builtin_amdgcn_s_setprio(1);
#pragma unroll
    for (int kk = 0; kk < 2; kk++)
#pragma unroll
      for (int c = 0; c < 2; c++)
#pragma unroll
        for (int qg = 0; qg < 2; qg++)
          sacc[c][qg] = MFMA32(kf[c][kk], qf[qg][kk], sacc[c][qg]);
    __builtin_amdgcn_s_setprio(0);

    // single-V buffer: dense 1KB wave-read issued here, consumed after the
    // ~400-cycle softmax below (L2 hit ~200 cyc -> hidden).
    bf16x8 vf[4];
#pragma unroll
    for (int dg = 0; dg < 4; dg++)
      vf[dg] = *(const bf16x8*)(Vw + j * 8192 + dg * 512);

    bf16x8 pfr[2];
    if (j == T - 1) {
      const int kb0 = j * 128 + w * 32 + quad * 8;   // + 4c + e = actual key
#pragma unroll
      for (int qg = 0; qg < 2; qg++) {
        const int qrow = q0 + qg * 16 + l15;
        bf16x8 pb;
#pragma unroll
        for (int c = 0; c < 2; c++)
#pragma unroll
          for (int e = 0; e < 4; e++) {
            float s = sacc[c][qg][e];
            if (kb0 + 4 * c + e > qrow) s = -1e30f;
            float pv = __builtin_amdgcn_exp2f(s);
            lsum[qg] += pv;
            pb[c * 4 + e] = (bf16)pv;
          }
        pfr[qg] = pb;
      }
    } else {
#pragma unroll
      for (int qg = 0; qg < 2; qg++) {
        bf16x8 pb;
#pragma unroll
        for (int c = 0; c < 2; c++)
#pragma unroll
          for (int e = 0; e < 4; e++) {
            float pv = __builtin_amdgcn_exp2f(sacc[c][qg][e]);
            lsum[qg] += pv;
            pb[c * 4 + e] = (bf16)pv;
          }
        pfr[qg] = pb;
      }
    }

    // O += P V  (K=32, P direct from registers)
    __builtin_amdgcn_s_setprio(1);
#pragma unroll
    for (int qg = 0; qg < 2; qg++)
#pragma unroll
      for (int dg = 0; dg < 4; dg++)
        oacc[qg][dg] = MFMA32(pfr[qg], vf[dg], oacc[qg][dg]);
    __builtin_amdgcn_s_setprio(0);
  };

  bf16x8 kfA[2][2], kfB[2][2];
  if (Tw > 0) {
    load_k(0, kfA);
    for (int j = 0; j < Tw; j += 2) {
      if (j + 1 < Tw) load_k(j + 1, kfB);
      compute(j, kfA);
      if (j + 2 < Tw) load_k(j + 2, kfA);
      if (j + 1 < Tw) compute(j + 1, kfB);
    }
  }

  // ---- cross-wave reduction: all 4 key-split waves share the same 32 rows ----
#pragma unroll
  for (int qg = 0; qg < 2; qg++)
    Lbuf[w][quad][qg * 16 + l15] = lsum[qg];

  const int row = tid >> 4;               // 0..15 (q within 16-row chunk)
  const int col = (tid & 15) * 4;         // 0..60 (d within head)
  for (int cp = 0; cp < 2; cp++) {        // chunk = qg index
#pragma unroll
    for (int dg = 0; dg < 4; dg++)
#pragma unroll
      for (int e = 0; e < 4; e++)
        Obuf[w][quad * 4 + e][dg * 16 + l15] = oacc[cp][dg][e];
    __syncthreads();                      // writes visible (covers Lbuf too)
    f32x4 os = {};
#pragma unroll
    for (int ww = 0; ww < 4; ww++)
      os += *(const f32x4*)&Obuf[ww][row][col];
    float lr = 0.f;
#pragma unroll
    for (int ww = 0; ww < 4; ww++)
#pragma unroll
      for (int qq = 0; qq < 4; qq++)
        lr += Lbuf[ww][qq][cp * 16 + row];
    const float linv = 1.f / lr;
    bf16x4 ob;
#pragma unroll
    for (int e2 = 0; e2 < 4; e2++) ob[e2] = (bf16)(os[e2] * linv);
    *(bf16x4*)(Ctx + (size_t)(q0 + cp * 16 + row) * DMODEL + hq + col) = ob;
    __syncthreads();                      // reads done before next chunk
  }
}

// ---------------- gemm_out: 64x128 tile, K=1024, BK=32, swizzled -----------
__global__ __launch_bounds__(256) void gemm_out(const bf16* __restrict__ A,
                                                const bf16* __restrict__ Bt,
                                                float* __restrict__ C,
                                                const float* __restrict__ bias) {
  __shared__ bf16 lsA[64 * 32];
  __shared__ bf16 lsB[128 * 32];
  const int tid = threadIdx.x, w = tid >> 6, lane = tid & 63;
  const int l15 = lane & 15, quad = lane >> 4;
  const int m0 = blockIdx.x * 64, n0 = blockIdx.y * 128;
  const int wm = (w >> 1) * 32, wn = (w & 1) * 64;
  const int rowA = lane >> 2;
  const int colk = (((lane & 3) ^ ((lane >> 3) & 3))) * 8;  // inverse-swizzled src
  const int rsl = (l15 >> 1) & 3;                           // read-side swizzle

  f32x4 acc[2][4] = {};

  for (int k0 = 0; k0 < 1024; k0 += 32) {
    __syncthreads();
#pragma unroll
    for (int i = 0; i < 3; i++) {
      int s = w * 3 + i;
      if (s < 4) {
        const bf16* ga = A + (size_t)(m0 + s * 16 + rowA) * 1024 + k0 + colk;
        GLOAD_LDS16(ga, lsA + s * 512);
      } else {
        const bf16* gb = Bt + (size_t)(n0 + (s - 4) * 16 + rowA) * 1024 + k0 + colk;
        GLOAD_LDS16(gb, lsB + (s - 4) * 512);
      }
    }
    __syncthreads();

    bf16x8 af[2], bfr[4];
#pragma unroll
    for (int r = 0; r < 2; r++)
      af[r] = *(const bf16x8*)(lsA + (wm + r * 16 + l15) * 32 + (quad ^ rsl) * 8);
#pragma unroll
    for (int c = 0; c < 4; c++)
      bfr[c] = *(const bf16x8*)(lsB + (wn + c * 16 + l15) * 32 + (quad ^ rsl) * 8);
#pragma unroll
    for (int r = 0; r < 2; r++)
#pragma unroll
      for (int c = 0; c < 4; c++)
        acc[r][c] = MFMA32(af[r], bfr[c], acc[r][c]);
  }

#pragma unroll
  for (int r = 0; r < 2; r++) {
#pragma unroll
    for (int c = 0; c < 4; c++) {
      int col = n0 + wn + c * 16 + l15;
#pragma unroll
      for (int e = 0; e < 4; e++) {
        int row = m0 + wm + r * 16 + quad * 4 + e;
        C[(size_t)row * 1024 + col] = acc[r][c][e] + bias[col];
      }
    }
  }
}

// ------------------------------- launcher ----------------------------------
extern "C" void kernel_launch(void* const* d_in, const int* in_sizes, int n_in,
                              void* d_out, int out_size, void* d_ws, size_t ws_size,
                              hipStream_t stream) {
  const float* x  = (const float*)d_in[0];
  const float* Wq = (const float*)d_in[1];
  const float* Wk = (const float*)d_in[2];
  const float* Wv = (const float*)d_in[3];
  const float* Wo = (const float*)d_in[4];
  const float* bo = (const float*)d_in[5];

  char* ws = (char*)d_ws;                    // 48 MB total
  bf16* xb  = (bf16*)(ws);                   // 8 MB  [4096][1024]
  bf16* Wt  = (bf16*)(ws + (8u  << 20));     // 6 MB  [3072][1024]
  bf16* Wot = (bf16*)(ws + (14u << 20));     // 2 MB  [1024][1024]
  bf16* Qb  = (bf16*)(ws + (16u << 20));     // 8 MB  [4096][1024]
  bf16* Kf  = (bf16*)(ws + (24u << 20));     // 8 MB  packed K frags
  bf16* Vf  = (bf16*)(ws + (32u << 20));     // 8 MB  packed V frags
  bf16* Ctx = (bf16*)(ws + (40u << 20));     // 8 MB  [4096][1024]

  preprocess<<<2048, 256, 0, stream>>>(x, Wq, Wk, Wv, Wo, xb, Wt, Wot);
  gemm_qkv<<<dim3(32, 24), 256, 0, stream>>>(xb, Wt, Qb, Kf, Vf);
  flash_attn<<<2048, 256, 0, stream>>>(Qb, Kf, Vf, Ctx);
  gemm_out<<<dim3(64, 8), 256, 0, stream>>>(Ctx, Wot, (float*)d_out, bo);
}

// Round 13
// 176.700 us; speedup vs baseline: 1.5440x; 1.0431x over previous
//
#include <hip/hip_runtime.h>
#include <hip/hip_bf16.h>
#include <stdint.h>

// ---------------------------------------------------------------------------
// MHA forward, bf16 MFMA path (gfx950).  B=1, S=4096, D=1024, H=16, HD=64.
//   1. preprocess ROUND-22: W-transpose vectorized — float4 reads -> LDS
//      (2-way bank aliasing = free) -> bf16x4 writes (512B/wave vs 128B
//      scalar before). x-cast unchanged (already float4/bf16x4).
//   2. gemm_qkv: R7 version frozen (BK=32; R10 A/B: BK=64 net -5 us).
//      Q -> Qb pre-scaled 0.125*log2e; K,V fragment-packed (R16).
//   3. flash_attn: R7 kernel FROZEN (best of 6 geometries, 46.5-48.9 us).
//      Ledger: R0 75 | R2 140 | R3 spill | R4 133 | R7 packed 46.5 |
//      R11 spill 142 | R12 32q+3waves 52.3. 64q/2-wave + packed K/V wins;
//      remaining 35% stall is issue-packing at 2 waves/SIMD (reg floor 188).
//   4. gemm_out ROUND-22: adopted gemm_qkv's proven 128x128/acc[4][4]
//      structure (was 64x128/acc[2][4] = half the MFMA per staging,
//      staging-bound). Grid (32,8) = 256 blocks.
// ---------------------------------------------------------------------------

typedef __bf16 bf16;
typedef __bf16 bf16x2_t __attribute__((ext_vector_type(2)));
typedef __bf16 bf16x4 __attribute__((ext_vector_type(4)));
typedef __bf16 bf16x8 __attribute__((ext_vector_type(8)));
typedef float  f32x4  __attribute__((ext_vector_type(4)));

#define MFMA32(a, b, c) __builtin_amdgcn_mfma_f32_16x16x32_bf16((a), (b), (c), 0, 0, 0)

static constexpr int S_LEN  = 4096;
static constexpr int DMODEL = 1024;
static constexpr int HDIM   = 64;

#define GLOAD_LDS16(g, l)                                                      \
  __builtin_amdgcn_global_load_lds((__attribute__((address_space(1))) void*)(g), \
                                   (__attribute__((address_space(3))) void*)(l), 16, 0, 0)

// ------------- fused preprocess: cast x + 4 weight transposes --------------
__global__ __launch_bounds__(256) void preprocess(const float* __restrict__ x,
                                                  const float* __restrict__ Wq,
                                                  const float* __restrict__ Wk,
                                                  const float* __restrict__ Wv,
                                                  const float* __restrict__ Wo,
                                                  bf16* __restrict__ xb,
                                                  bf16* __restrict__ Wt,
                                                  bf16* __restrict__ Wot) {
  __shared__ float tile[64][65];
  const int t = threadIdx.x, b = blockIdx.x;
  if (b < 1024) {
#pragma unroll
    for (int i = 0; i < 4; i++) {
      int idx = b * 1024 + i * 256 + t;
      float4 v = ((const float4*)x)[idx];
      bf16x4 o;
      o[0] = (bf16)v.x; o[1] = (bf16)v.y; o[2] = (bf16)v.z; o[3] = (bf16)v.w;
      ((bf16x4*)xb)[idx] = o;
    }
    return;
  }
  const int id = b - 1024;
  const int wsel = id >> 8;
  const int t2 = id & 255;
  const int kb = (t2 & 15) * 64, nb = (t2 >> 4) * 64;
  const float* src = (wsel == 0) ? Wq : (wsel == 1) ? Wk : (wsel == 2) ? Wv : Wo;
  bf16* dst = (wsel < 3) ? (Wt + (size_t)wsel * 1024 * 1024) : Wot;
  // read: 4 iters of float4 (1KB/wave), LDS banks 2-way (free)
#pragma unroll
  for (int i = 0; i < 4; i++) {
    int idx = t + i * 256;                 // 0..1023
    int r = idx >> 4, c4 = (idx & 15) * 4;
    float4 v = *(const float4*)&src[(size_t)(kb + r) * 1024 + nb + c4];
    tile[r][c4] = v.x; tile[r][c4 + 1] = v.y;
    tile[r][c4 + 2] = v.z; tile[r][c4 + 3] = v.w;
  }
  __syncthreads();
  // write: 4 iters of bf16x4 along the contiguous (kb+rr) direction
#pragma unroll
  for (int i = 0; i < 4; i++) {
    int idx = t + i * 256;
    int cc = idx >> 4, rr4 = (idx & 15) * 4;
    bf16x4 o;
    o[0] = (bf16)tile[rr4][cc];     o[1] = (bf16)tile[rr4 + 1][cc];
    o[2] = (bf16)tile[rr4 + 2][cc]; o[3] = (bf16)tile[rr4 + 3][cc];
    *(bf16x4*)&dst[(size_t)(nb + cc) * 1024 + kb + rr4] = o;
  }
}

// ------------------- gemm_qkv: 128x128 tile, K=1024, BK=32 -----------------
// R7 version (frozen). Outputs:
//   n0 <  1024 : Qb[row][col] = acc * 0.18033688 (0.125*log2e), stride 1024
//   n0 <  2048 : Kf packed (R16 layout)
//   else       : Vf packed (R16 layout)
__global__ __launch_bounds__(256) void gemm_qkv(const bf16* __restrict__ A,
                                                const bf16* __restrict__ Bt,
                                                bf16* __restrict__ Qb,
                                                bf16* __restrict__ Kf,
                                                bf16* __restrict__ Vf) {
  __shared__ bf16 lsA[128 * 32];
  __shared__ bf16 lsB[128 * 32];
  const int tid = threadIdx.x, w = tid >> 6, lane = tid & 63;
  const int l15 = lane & 15, quad = lane >> 4;
  const int m0 = blockIdx.x * 128, n0 = blockIdx.y * 128;
  const int wm = (w >> 1) * 64, wn = (w & 1) * 64;
  const int rowA = lane >> 2;
  const int colk = (((lane & 3) ^ ((lane >> 3) & 3))) * 8;  // inverse-swizzled src
  const int rsl = (l15 >> 1) & 3;                           // read-side swizzle

  f32x4 acc[4][4] = {};

  for (int k0 = 0; k0 < 1024; k0 += 32) {
    __syncthreads();
#pragma unroll
    for (int i = 0; i < 2; i++) {
      int s = w * 2 + i;
      const bf16* ga = A + (size_t)(m0 + s * 16 + rowA) * 1024 + k0 + colk;
      GLOAD_LDS16(ga, lsA + s * 512);
      const bf16* gb = Bt + (size_t)(n0 + s * 16 + rowA) * 1024 + k0 + colk;
      GLOAD_LDS16(gb, lsB + s * 512);
    }
    __syncthreads();

    bf16x8 af[4], bfr[4];
#pragma unroll
    for (int r = 0; r < 4; r++)
      af[r] = *(const bf16x8*)(lsA + (wm + r * 16 + l15) * 32 + (quad ^ rsl) * 8);
#pragma unroll
    for (int c = 0; c < 4; c++)
      bfr[c] = *(const bf16x8*)(lsB + (wn + c * 16 + l15) * 32 + (quad ^ rsl) * 8);
#pragma unroll
    for (int r = 0; r < 4; r++)
#pragma unroll
      for (int c = 0; c < 4; c++)
        acc[r][c] = MFMA32(af[r], bfr[c], acc[r][c]);
  }

  if (n0 < 1024) {
    // ---- Q ----
#pragma unroll
    for (int r = 0; r < 4; r++) {
#pragma unroll
      for (int c = 0; c < 4; c++) {
        int col = n0 + wn + c * 16 + l15;
#pragma unroll
        for (int e = 0; e < 4; e++) {
          int row = m0 + wm + r * 16 + quad * 4 + e;
          Qb[(size_t)row * 1024 + col] = (bf16)(acc[r][c][e] * 0.18033688f);
        }
      }
    }
  } else if (n0 < 2048) {
    // ---- K packed ----
    const int h  = (n0 - 1024 + wn) >> 6;
    const int g0 = (m0 + wm) >> 5;
    bf16* base = Kf + (size_t)(h * 128 + g0) * 2048 +
                 (quad & 1) * 1024 + (l15 >> 3) * 128 + (quad >> 1) * 32 + (l15 & 7);
#pragma unroll
    for (int r = 0; r < 4; r++) {
#pragma unroll
      for (int c = 0; c < 4; c++) {
#pragma unroll
        for (int e = 0; e < 4; e++) {
          base[(r >> 1) * 2048 + (r & 1) * 64 + (c >> 1) * 512 + (c & 1) * 256 + e * 8] =
              (bf16)acc[r][c][e];
        }
      }
    }
  } else {
    // ---- V packed ----
    const int h  = (n0 - 2048 + wn) >> 6;
    const int g0 = (m0 + wm) >> 5;
    bf16* base = Vf + (size_t)(h * 128 + g0) * 2048 +
                 (quad >> 1) * 128 + l15 * 8 + (quad & 1) * 4;
#pragma unroll
    for (int r = 0; r < 4; r++) {
#pragma unroll
      for (int c = 0; c < 4; c++) {
        bf16x4 pk;
#pragma unroll
        for (int e = 0; e < 4; e++) pk[e] = (bf16)acc[r][c][e];
        *(bf16x4*)(base + (r >> 1) * 2048 + (r & 1) * 256 + c * 512) = pk;
      }
    }
  }
}

// ----------------------------- flash attention -----------------------------
// R7 kernel FROZEN (measured 46.5-48.9 us). 1024 blocks, one 64-q tile each,
// 4 key-split waves, K+V register ping-pong, permuted S^T packing, chunked
// reduction. K/V loads from fragment-packed Kf/Vf: dense 1KB wave-reads.
__global__ __launch_bounds__(256, 2) void flash_attn(const bf16* __restrict__ Qb,
                                                     const bf16* __restrict__ Kf,
                                                     const bf16* __restrict__ Vf,
                                                     bf16* __restrict__ Ctx) {
  __shared__ float Obuf[4][16][68];   // 17.4 KB: per-wave partial O, one qg chunk
  __shared__ float Lbuf[4][4][64];    // 4 KB
  const int tid = threadIdx.x, w = tid >> 6, lane = tid & 63;
  const int l15 = lane & 15, quad = lane >> 4;
  const int i = blockIdx.x;
  const int head = (i & 7) + 8 * ((i >> 3) & 1);
  const int qt_raw = i >> 4;
  const int qb = (qt_raw < 32) ? qt_raw : (95 - qt_raw);
  const int hq = head * HDIM;

  const int T = (qb >> 1) + 1;              // 128-key tiles

  // Packed per-wave base pointers: group g = j*4 + w.
  const bf16* Kw = Kf + (size_t)(head * 128 + w) * 2048 + lane * 8;
  const bf16* Vw = Vf + (size_t)(head * 128 + w) * 2048 + lane * 8;

  // Q frags (B-operand): q = qb*64 + qg*16 + l15, d = kk*32 + quad*8 + j
  bf16x8 qf[4][2];
#pragma unroll
  for (int qg = 0; qg < 4; qg++)
#pragma unroll
    for (int kk = 0; kk < 2; kk++)
      qf[qg][kk] = *(const bf16x8*)(Qb + (size_t)(qb * 64 + qg * 16 + l15) * 1024 +
                                    hq + kk * 32 + quad * 8);

  f32x4 oacc[4][4] = {};
  float lsum[4] = {0.f, 0.f, 0.f, 0.f};

  auto load_k = [&](int j, bf16x8 (&kf)[2][2]) {
#pragma unroll
    for (int c = 0; c < 2; c++)
#pragma unroll
      for (int kk = 0; kk < 2; kk++)
        kf[c][kk] = *(const bf16x8*)(Kw + j * 8192 + c * 1024 + kk * 512);
  };
  auto load_v = [&](int j, bf16x8 (&vf)[4]) {
#pragma unroll
    for (int dg = 0; dg < 4; dg++)
      vf[dg] = *(const bf16x8*)(Vw + j * 8192 + dg * 512);
  };
  auto compute = [&](int j, bf16x8 (&kf)[2][2], bf16x8 (&vf)[4]) {
    // S^T = K Q^T : C row = key-slot quad*4+e (matrix c), col = q = l15
    f32x4 sacc[2][4] = {};
    __builtin_amdgcn_s_setprio(1);
#pragma unroll
    for (int kk = 0; kk < 2; kk++)
#pragma unroll
      for (int c = 0; c < 2; c++)
#pragma unroll
        for (int qg = 0; qg < 4; qg++)
          sacc[c][qg] = MFMA32(kf[c][kk], qf[qg][kk], sacc[c][qg]);
    __builtin_amdgcn_s_setprio(0);

    bf16x8 pfr[4];
    if (j == T - 1) {
      const int kb0 = j * 128 + w * 32 + quad * 8;   // + 4c + e = actual key
#pragma unroll
      for (int qg = 0; qg < 4; qg++) {
        const int qrow = qb * 64 + qg * 16 + l15;
        bf16x8 pb;
#pragma unroll
        for (int c = 0; c < 2; c++)
#pragma unroll
          for (int e = 0; e < 4; e++) {
            float s = sacc[c][qg][e];
            if (kb0 + 4 * c + e > qrow) s = -1e30f;
            float pv = __builtin_amdgcn_exp2f(s);
            lsum[qg] += pv;
            pb[c * 4 + e] = (bf16)pv;
          }
        pfr[qg] = pb;
      }
    } else {
#pragma unroll
      for (int qg = 0; qg < 4; qg++) {
        bf16x8 pb;
#pragma unroll
        for (int c = 0; c < 2; c++)
#pragma unroll
          for (int e = 0; e < 4; e++) {
            float pv = __builtin_amdgcn_exp2f(sacc[c][qg][e]);
            lsum[qg] += pv;
            pb[c * 4 + e] = (bf16)pv;
          }
        pfr[qg] = pb;
      }
    }

    // O += P V  (K=32, P direct from registers)
    __builtin_amdgcn_s_setprio(1);
#pragma unroll
    for (int qg = 0; qg < 4; qg++)
#pragma unroll
      for (int dg = 0; dg < 4; dg++)
        oacc[qg][dg] = MFMA32(pfr[qg], vf[dg], oacc[qg][dg]);
    __builtin_amdgcn_s_setprio(0);
  };

  bf16x8 kfA[2][2], vfA[4], kfB[2][2], vfB[4];
  load_k(0, kfA); load_v(0, vfA);
  for (int j = 0; j < T; j += 2) {
    if (j + 1 < T) { load_k(j + 1, kfB); load_v(j + 1, vfB); }
    compute(j, kfA, vfA);
    if (j + 2 < T) { load_k(j + 2, kfA); load_v(j + 2, vfA); }
    if (j + 1 < T) compute(j + 1, kfB, vfB);
  }

  // ---- chunked cross-wave reduction: one qg (16 q-rows) at a time ----
#pragma unroll
  for (int qg = 0; qg < 4; qg++)
    Lbuf[w][quad][qg * 16 + l15] = lsum[qg];

  const int row = tid >> 4;               // 0..15 (local q within chunk)
  const int col = (tid & 15) * 4;         // 0..60 (d within head)
  for (int qg = 0; qg < 4; qg++) {
#pragma unroll
    for (int dg = 0; dg < 4; dg++)
#pragma unroll
      for (int e = 0; e < 4; e++)
        Obuf[w][quad * 4 + e][dg * 16 + l15] = oacc[qg][dg][e];
    __syncthreads();                      // writes visible
    f32x4 os = {};
#pragma unroll
    for (int ww = 0; ww < 4; ww++)
      os += *(const f32x4*)&Obuf[ww][row][col];
    float lr = 0.f;
#pragma unroll
    for (int ww = 0; ww < 4; ww++)
#pragma unroll
      for (int qq = 0; qq < 4; qq++)
        lr += Lbuf[ww][qq][qg * 16 + row];
    const float linv = 1.f / lr;
    bf16x4 ob;
#pragma unroll
    for (int e2 = 0; e2 < 4; e2++) ob[e2] = (bf16)(os[e2] * linv);
    *(bf16x4*)(Ctx + (size_t)(qb * 64 + qg * 16 + row) * DMODEL + hq + col) = ob;
    __syncthreads();                      // reads done before next chunk
  }
}

// ------------- gemm_out: 128x128 tile, K=1024, BK=32 (R22) -----------------
// Same structure as gemm_qkv (acc[4][4] = 2x the MFMA per staging of the old
// 64x128 version). Grid (32,8) = 256 blocks. fp32 out + bias.
__global__ __launch_bounds__(256) void gemm_out(const bf16* __restrict__ A,
                                                const bf16* __restrict__ Bt,
                                                float* __restrict__ C,
                                                const float* __restrict__ bias) {
  __shared__ bf16 lsA[128 * 32];
  __shared__ bf16 lsB[128 * 32];
  const int tid = threadIdx.x, w = tid >> 6, lane = tid & 63;
  const int l15 = lane & 15, quad = lane >> 4;
  const int m0 = blockIdx.x * 128, n0 = blockIdx.y * 128;
  const int wm = (w >> 1) * 64, wn = (w & 1) * 64;
  const int rowA = lane >> 2;
  const int colk = (((lane & 3) ^ ((lane >> 3) & 3))) * 8;  // inverse-swizzled src
  const int rsl = (l15 >> 1) & 3;                           // read-side swizzle

  f32x4 acc[4][4] = {};

  for (int k0 = 0; k0 < 1024; k0 += 32) {
    __syncthreads();
#pragma unroll
    for (int i = 0; i < 2; i++) {
      int s = w * 2 + i;
      const bf16* ga = A + (size_t)(m0 + s * 16 + rowA) * 1024 + k0 + colk;
      GLOAD_LDS16(ga, lsA + s * 512);
      const bf16* gb = Bt + (size_t)(n0 + s * 16 + rowA) * 1024 + k0 + colk;
      GLOAD_LDS16(gb, lsB + s * 512);
    }
    __syncthreads();

    bf16x8 af[4], bfr[4];
#pragma unroll
    for (int r = 0; r < 4; r++)
      af[r] = *(const bf16x8*)(lsA + (wm + r * 16 + l15) * 32 + (quad ^ rsl) * 8);
#pragma unroll
    for (int c = 0; c < 4; c++)
      bfr[c] = *(const bf16x8*)(lsB + (wn + c * 16 + l15) * 32 + (quad ^ rsl) * 8);
#pragma unroll
    for (int r = 0; r < 4; r++)
#pragma unroll
      for (int c = 0; c < 4; c++)
        acc[r][c] = MFMA32(af[r], bfr[c], acc[r][c]);
  }

#pragma unroll
  for (int r = 0; r < 4; r++) {
#pragma unroll
    for (int c = 0; c < 4; c++) {
      int col = n0 + wn + c * 16 + l15;
      float bv = bias[col];
#pragma unroll
      for (int e = 0; e < 4; e++) {
        int row = m0 + wm + r * 16 + quad * 4 + e;
        C[(size_t)row * 1024 + col] = acc[r][c][e] + bv;
      }
    }
  }
}

// ------------------------------- launcher ----------------------------------
extern "C" void kernel_launch(void* const* d_in, const int* in_sizes, int n_in,
                              void* d_out, int out_size, void* d_ws, size_t ws_size,
                              hipStream_t stream) {
  const float* x  = (const float*)d_in[0];
  const float* Wq = (const float*)d_in[1];
  const float* Wk = (const float*)d_in[2];
  const float* Wv = (const float*)d_in[3];
  const float* Wo = (const float*)d_in[4];
  const float* bo = (const float*)d_in[5];

  char* ws = (char*)d_ws;                    // 48 MB total
  bf16* xb  = (bf16*)(ws);                   // 8 MB  [4096][1024]
  bf16* Wt  = (bf16*)(ws + (8u  << 20));     // 6 MB  [3072][1024]
  bf16* Wot = (bf16*)(ws + (14u << 20));     // 2 MB  [1024][1024]
  bf16* Qb  = (bf16*)(ws + (16u << 20));     // 8 MB  [4096][1024]
  bf16* Kf  = (bf16*)(ws + (24u << 20));     // 8 MB  packed K frags
  bf16* Vf  = (bf16*)(ws + (32u << 20));     // 8 MB  packed V frags
  bf16* Ctx = (bf16*)(ws + (40u << 20));     // 8 MB  [4096][1024]

  preprocess<<<2048, 256, 0, stream>>>(x, Wq, Wk, Wv, Wo, xb, Wt, Wot);
  gemm_qkv<<<dim3(32, 24), 256, 0, stream>>>(xb, Wt, Qb, Kf, Vf);
  flash_attn<<<1024, 256, 0, stream>>>(Qb, Kf, Vf, Ctx);
  gemm_out<<<dim3(32, 8), 256, 0, stream>>>(Ctx, Wot, (float*)d_out, bo);
}